// Round 13
// baseline (27.689 us; speedup 1.0000x reference)
//
#include <hip/hip_runtime.h>
#include <math.h>

#define F_LEN 21
#define D_LEN 41
#define S_LEN 61                 // F_LEN + D_LEN - 1
#define ROWS 64                  // rows per block
#define THREADS 256              // 4 threads per row
#define NELEM (ROWS * S_LEN)     // 3904 float2 slots
#define NV4   (NELEM / 4)        // 976 float4 per input array
#define DOUT  (ROWS * D_LEN)     // 2624 dist floats
#define DV4   (DOUT / 4)         // 656
#define LFP   24                 // lf table row pitch (floats)
#define NDP   11                 // max d's per thread (q==3)

// R12 structure with ONE change: 4 threads/row instead of 8. Each thread
// owns d = q*10 .. q*10+9 (q==3 also d=40) over a 31-column window.
// Per-row LDS product-reads drop 208 -> 124 (-40% on the co-critical LDS
// pipe); total VALU invariant. prod[11]+lfr[21] static -> ~60 regs.
__global__ __launch_bounds__(THREADS, 4) void bp_kernel(
    const float* __restrict__ pf_g, const float* __restrict__ pb_g,
    const float* __restrict__ slop_g, const float* __restrict__ amp_g,
    float* __restrict__ out_dist, float* __restrict__ out_mean,
    float* __restrict__ out_ivar)
{
    __shared__ float2 lds_fb[NELEM];          // 31232 B; reused for dist stage
    __shared__ float  lfL[ROWS * LFP];        // 6144 B

    const int tid  = threadIdx.x;
    const int rl   = tid >> 2;                // local row 0..63
    const int q    = tid & 3;                 // quadrant within row
    const int row0 = blockIdx.x * ROWS;
    const int r    = row0 + rl;

    // ---- staging: float4 global loads -> interleaved float2 LDS ----------
    const float4* pf4 = (const float4*)(pf_g + (size_t)row0 * S_LEN);
    const float4* pb4 = (const float4*)(pb_g + (size_t)row0 * S_LEN);
    #pragma unroll
    for (int it = 0; it < 4; ++it) {
        int idx4 = it * THREADS + tid;        // 0..975
        if (idx4 < NV4) {
            float4 f = pf4[idx4];
            float4 b = pb4[idx4];
            lds_fb[idx4 * 4 + 0] = make_float2(f.x, b.x);
            lds_fb[idx4 * 4 + 1] = make_float2(f.y, b.y);
            lds_fb[idx4 * 4 + 2] = make_float2(f.z, b.z);
            lds_fb[idx4 * 4 + 3] = make_float2(f.w, b.w);
        }
    }

    // ---- per-row scalars + cooperative lf build (under staging latency) --
    const float a  = amp_g[r];
    const float sl = slop_g[r];
    float* lfp = lfL + rl * LFP;
    {
        const float invs = 1.0f / sl;
        const int k1 = 2 * q + 1;             // 1,3,5,7
        const int k2 = 2 * q + 2;             // 2,4,6,8
        float E1 = __expf((float)k1 * invs);
        float t1 = __fdividef(E1 - 1.0f, E1 + 1.0f);
        float d1 = a * t1;
        lfp[10 + k1] = 0.5f - d1;
        lfp[10 - k1] = 0.5f + d1;
        float E2 = __expf((float)k2 * invs);
        float t2 = __fdividef(E2 - 1.0f, E2 + 1.0f);
        float d2 = a * t2;
        lfp[10 + k2] = 0.5f - d2;
        lfp[10 - k2] = 0.5f + d2;
        if (q < 2) {
            const int k3 = 9 + q;             // 9,10
            float E3 = __expf((float)k3 * invs);
            float t3 = __fdividef(E3 - 1.0f, E3 + 1.0f);
            float d3 = a * t3;
            lfp[10 + k3] = 0.5f - d3;
            lfp[10 - k3] = 0.5f + d3;
        }
        if (q == 0) lfp[10] = 0.5f;
    }

    __syncthreads();

    // ---- column-streaming product over this thread's window --------------
    const int  d0    = q * 10;                // 0,10,20,30
    const bool has11 = (q == 3);
    const int  base  = rl * S_LEN + d0;

    float lfr[F_LEN];                          // filled during i<21
    float prod[NDP];
    #pragma unroll
    for (int dp = 0; dp < NDP; ++dp) prod[dp] = 1.0f;

    #pragma unroll
    for (int i = 0; i < 31; ++i) {            // column s = d0 + i
        if (i < F_LEN) lfr[i] = lfp[i];       // one ds_read_b32 (broadcast)
        float2 fb = lds_fb[base + i];         // one ds_read_b64
        float  df = fb.x - fb.y;
        #pragma unroll
        for (int dp = 0; dp < NDP; ++dp) {
            const int j = i - dp;             // compile-time constant
            if (j >= 0 && j < F_LEN) {
                float t = fmaf(lfr[j], df, fb.y);
                if (dp == 10) t = has11 ? t : 1.0f;
                prod[dp] *= t;
            }
        }
    }

    // ---- partial moments + 4-lane butterfly ------------------------------
    const float df0 = (float)d0;
    float s0 = 0.0f, s1 = 0.0f, s2 = 0.0f;
    #pragma unroll
    for (int dp = 0; dp < NDP; ++dp) {
        float p = prod[dp];
        if (dp == 10) p = has11 ? p : 0.0f;
        float dv = df0 + (float)dp;
        s0 += p;
        s1 += dv * p;
        s2 += dv * dv * p;
    }
    #pragma unroll
    for (int w = 1; w < 4; w <<= 1) {
        s0 += __shfl_xor(s0, w, 64);
        s1 += __shfl_xor(s1, w, 64);
        s2 += __shfl_xor(s2, w, 64);
    }

    const float inv      = 1.0f / fmaxf(s0, 1e-12f);
    const float mean_tmp = s1 * inv;
    const float m2       = s2 * inv;
    const float var_tmp  = fmaf(-mean_tmp, mean_tmp, m2);

    if (q == 0) {
        const float two_a = 2.0f * a;
        const float at    = 0.5f * __logf((1.0f + two_a) / (1.0f - two_a));
        const float min_v = fmaxf(0.5f / (at * at), sl);
        const float var   = fmaxf(var_tmp, min_v);
        out_mean[r] = mean_tmp - (float)((D_LEN - 1) / 2);
        out_ivar[r] = 1.0f / var;
    }

    // ---- dist: stage normalized values in LDS, then float4 copy-out ------
    __syncthreads();                          // all reads of lds_fb done
    float* ldsd = (float*)lds_fb;             // alias: 2624 floats needed
    #pragma unroll
    for (int dp = 0; dp < 10; ++dp)
        ldsd[rl * D_LEN + d0 + dp] = prod[dp] * inv;
    if (has11)
        ldsd[rl * D_LEN + 40] = prod[10] * inv;
    __syncthreads();

    const float4* ld4 = (const float4*)ldsd;
    float4* o4 = (float4*)(out_dist + (size_t)row0 * D_LEN);  // 16B aligned
    #pragma unroll
    for (int it = 0; it < 3; ++it) {
        int idx4 = it * THREADS + tid;        // 0..655
        if (idx4 < DV4) o4[idx4] = ld4[idx4];
    }
}

extern "C" void kernel_launch(void* const* d_in, const int* in_sizes, int n_in,
                              void* d_out, int out_size, void* d_ws, size_t ws_size,
                              hipStream_t stream) {
    // inputs: [0] lines_feature (unused), [1] pf, [2] pb, [3] slop, [4] amp
    const float* pf   = (const float*)d_in[1];
    const float* pb   = (const float*)d_in[2];
    const float* slop = (const float*)d_in[3];
    const float* amp  = (const float*)d_in[4];

    const int rows = in_sizes[3];              // B * L = 131072

    float* out_dist = (float*)d_out;
    float* out_mean = out_dist + (size_t)rows * D_LEN;
    float* out_ivar = out_mean + rows;

    const int blocks = rows / ROWS;            // 2048
    bp_kernel<<<blocks, THREADS, 0, stream>>>(pf, pb, slop, amp,
                                              out_dist, out_mean, out_ivar);
}

// Round 14
// 25.058 us; speedup vs baseline: 1.1050x; 1.1050x over previous
//
#include <hip/hip_runtime.h>
#include <math.h>

#define F_LEN 21
#define D_LEN 41
#define S_LEN 61                 // F_LEN + D_LEN - 1
#define ROWS 8                   // rows per block (one wave)
#define THREADS 64               // single-wave blocks: no inter-wave barrier
#define NELEM (ROWS * S_LEN)     // 488 float2 slots
#define NV4   (NELEM / 4)        // 122 float4 per input array
#define DOUT  (ROWS * D_LEN)     // 328 dist floats
#define DV4   (DOUT / 4)         // 82
#define LFP   24                 // lf table row pitch (floats)

// R12 structure verbatim at single-wave granularity. Theory: 256-thread
// blocks phase-lock into whole-CU load/compute convoys (HBM idles during
// compute); 16-32 independent 1-wave blocks per CU at staggered phases let
// TLP overlap memory and compute. All intra-row communication (lf build,
// butterfly) is intra-wave by construction.
__global__ __launch_bounds__(THREADS, 4) void bp_kernel(
    const float* __restrict__ pf_g, const float* __restrict__ pb_g,
    const float* __restrict__ slop_g, const float* __restrict__ amp_g,
    float* __restrict__ out_dist, float* __restrict__ out_mean,
    float* __restrict__ out_ivar)
{
    __shared__ float2 lds_fb[NELEM];          // 3904 B; reused for dist stage
    __shared__ float  lfL[ROWS * LFP];        // 768 B

    const int tid  = threadIdx.x;
    const int rl   = tid >> 3;                // local row 0..7
    const int q    = tid & 7;                 // octant within row
    const int row0 = blockIdx.x * ROWS;
    const int r    = row0 + rl;

    // ---- staging: float4 global loads -> interleaved float2 LDS ----------
    const float4* pf4 = (const float4*)(pf_g + (size_t)row0 * S_LEN);
    const float4* pb4 = (const float4*)(pb_g + (size_t)row0 * S_LEN);
    #pragma unroll
    for (int it = 0; it < 2; ++it) {
        int idx4 = it * THREADS + tid;        // 0..121
        if (idx4 < NV4) {
            float4 f = pf4[idx4];
            float4 b = pb4[idx4];
            lds_fb[idx4 * 4 + 0] = make_float2(f.x, b.x);
            lds_fb[idx4 * 4 + 1] = make_float2(f.y, b.y);
            lds_fb[idx4 * 4 + 2] = make_float2(f.z, b.z);
            lds_fb[idx4 * 4 + 3] = make_float2(f.w, b.w);
        }
    }

    // ---- per-row scalars + cooperative lf build (under staging latency) --
    const float a  = amp_g[r];
    const float sl = slop_g[r];
    float* lfp = lfL + rl * LFP;
    {
        const int k = q + 1;                  // k = 1..8
        float Ek = __expf((float)k / sl);     // e^{k/slop}
        float t  = __fdividef(Ek - 1.0f, Ek + 1.0f);   // tanh(k/(2*slop))
        float dl = a * t;
        lfp[10 + k] = 0.5f - dl;
        lfp[10 - k] = 0.5f + dl;
        if (q < 2) {
            const int k2 = q + 9;             // k = 9,10
            float Ek2 = __expf((float)k2 / sl);
            float t2  = __fdividef(Ek2 - 1.0f, Ek2 + 1.0f);
            float dl2 = a * t2;
            lfp[10 + k2] = 0.5f - dl2;
            lfp[10 - k2] = 0.5f + dl2;
        }
        if (q == 0) lfp[10] = 0.5f;
    }

    __syncthreads();                          // single-wave: near-free

    // ---- column-streaming product over this thread's window --------------
    const int  d0   = q * 5;
    const bool has6 = (q == 7);
    const int  base = rl * S_LEN + d0;

    float lfr[F_LEN];                          // rolling window registers
    float prod[6] = {1.0f, 1.0f, 1.0f, 1.0f, 1.0f, 1.0f};
    #pragma unroll
    for (int i = 0; i < 26; ++i) {            // column s = d0 + i
        if (i < F_LEN) lfr[i] = lfp[i];       // one ds_read_b32 (broadcast)
        float2 fb = lds_fb[base + i];         // one ds_read_b64
        float  df = fb.x - fb.y;
        #pragma unroll
        for (int dp = 0; dp < 6; ++dp) {
            const int j = i - dp;             // compile-time constant
            if (j >= 0 && j < F_LEN) {
                float t = fmaf(lfr[j], df, fb.y);
                if (dp == 5) t = has6 ? t : 1.0f;
                prod[dp] *= t;
            }
        }
    }

    // ---- partial moments + 8-lane butterfly ------------------------------
    const float df0 = (float)d0;
    float s0 = 0.0f, s1 = 0.0f, s2 = 0.0f;
    #pragma unroll
    for (int dp = 0; dp < 6; ++dp) {
        float p = prod[dp];
        if (dp == 5) p = has6 ? p : 0.0f;
        float dv = df0 + (float)dp;
        s0 += p;
        s1 += dv * p;
        s2 += dv * dv * p;
    }
    #pragma unroll
    for (int w = 1; w < 8; w <<= 1) {
        s0 += __shfl_xor(s0, w, 64);
        s1 += __shfl_xor(s1, w, 64);
        s2 += __shfl_xor(s2, w, 64);
    }

    const float inv      = 1.0f / fmaxf(s0, 1e-12f);
    const float mean_tmp = s1 * inv;
    const float m2       = s2 * inv;
    const float var_tmp  = fmaf(-mean_tmp, mean_tmp, m2);

    if (q == 0) {
        const float two_a = 2.0f * a;
        const float at    = 0.5f * __logf((1.0f + two_a) / (1.0f - two_a));
        const float min_v = fmaxf(0.5f / (at * at), sl);
        const float var   = fmaxf(var_tmp, min_v);
        out_mean[r] = mean_tmp - (float)((D_LEN - 1) / 2);
        out_ivar[r] = 1.0f / var;
    }

    // ---- dist: stage normalized values in LDS, then float4 copy-out ------
    __syncthreads();                          // all reads of lds_fb done
    float* ldsd = (float*)lds_fb;             // alias: 328 floats needed
    #pragma unroll
    for (int dp = 0; dp < 5; ++dp)
        ldsd[rl * D_LEN + d0 + dp] = prod[dp] * inv;
    if (has6)
        ldsd[rl * D_LEN + 40] = prod[5] * inv;
    __syncthreads();

    const float4* ld4 = (const float4*)ldsd;
    float4* o4 = (float4*)(out_dist + (size_t)row0 * D_LEN);  // 16B aligned
    #pragma unroll
    for (int it = 0; it < 2; ++it) {
        int idx4 = it * THREADS + tid;        // 0..81
        if (idx4 < DV4) o4[idx4] = ld4[idx4];
    }
}

extern "C" void kernel_launch(void* const* d_in, const int* in_sizes, int n_in,
                              void* d_out, int out_size, void* d_ws, size_t ws_size,
                              hipStream_t stream) {
    // inputs: [0] lines_feature (unused), [1] pf, [2] pb, [3] slop, [4] amp
    const float* pf   = (const float*)d_in[1];
    const float* pb   = (const float*)d_in[2];
    const float* slop = (const float*)d_in[3];
    const float* amp  = (const float*)d_in[4];

    const int rows = in_sizes[3];              // B * L = 131072

    float* out_dist = (float*)d_out;
    float* out_mean = out_dist + (size_t)rows * D_LEN;
    float* out_ivar = out_mean + rows;

    const int blocks = rows / ROWS;            // 16384
    bp_kernel<<<blocks, THREADS, 0, stream>>>(pf, pb, slop, amp,
                                              out_dist, out_mean, out_ivar);
}